// Round 13
// baseline (240.256 us; speedup 1.0000x reference)
//
#include <hip/hip_runtime.h>

// Constellation CNN. conv2 32x32x16 (dy-hoisted), conv3 16x16x32 with (mg,rq) wave
// split (B-reads deduped 2x, LDS floor below MFMA floor), fc fused MFMA. NHWC.

typedef short s16x8 __attribute__((ext_vector_type(8)));
typedef float f32x4 __attribute__((ext_vector_type(4)));
typedef float f32x16 __attribute__((ext_vector_type(16)));
typedef unsigned u32x4 __attribute__((ext_vector_type(4)));
typedef unsigned u32x2 __attribute__((ext_vector_type(2)));

__device__ __forceinline__ float prelu(float v, float a) {
    return v > 0.0f ? v : a * v;
}
__device__ __forceinline__ unsigned short bf16_rn(float x) {
    union { float f; unsigned u; } a; a.f = x;
    unsigned r = a.u + 0x7FFF + ((a.u >> 16) & 1);
    return (unsigned short)(r >> 16);
}
__device__ __forceinline__ unsigned pack2(float lo, float hi) {
    return (unsigned)bf16_rn(lo) | ((unsigned)bf16_rn(hi) << 16);
}

// ---------------- Kernel 1: [prepack blocks] + [scatter->conv1->pool blocks] ----------------
__global__ __launch_bounds__(256) void k_front(
    const float* __restrict__ x, const float* __restrict__ w1,
    const float* __restrict__ b1, const float* __restrict__ a1,
    unsigned short* __restrict__ out1, int b0, int np,
    const float* __restrict__ w3, unsigned short* __restrict__ w3pk,
    const float* __restrict__ w2, unsigned short* __restrict__ w2pk,
    const float* __restrict__ wc1, unsigned short* __restrict__ wf1pk,
    const float* __restrict__ wc2, unsigned short* __restrict__ wf2pk)
{
    const int t = threadIdx.x;
    if ((int)blockIdx.x < np) {
        const int bid = blockIdx.x;
        if (bid < 800) {
            int e = bid * 256 + t;
            int i  = e & 7;
            int co = (e >> 3) & 127;
            int g  = (e >> 10) & 3;
            int kk = (e >> 12) & 1;
            int tp = e >> 13;
            int ci = kk * 32 + g * 8 + i;
            w3pk[e] = bf16_rn(w3[((size_t)co * 64 + ci) * 25 + tp]);
        } else if (bid < 872) {
            int e = (bid - 800) * 256 + t;
            int i   = e & 7;
            int l   = (e >> 3) & 63;
            int mt  = (e >> 9) & 1;
            int kkk = (e >> 10) & 1;
            int tap = e >> 11;
            int co = mt * 32 + (l & 31);
            int ci = kkk * 16 + (l >> 5) * 8 + i;
            w2pk[e] = bf16_rn(w2[((size_t)co * 32 + ci) * 9 + tap]);
        } else if (bid < 2920) {
            int e = (bid - 872) * 256 + t;
            int i   = e & 7;
            int hid = (e >> 3) & 255;
            int g   = (e >> 11) & 3;
            int kc  = e >> 13;
            int k = kc * 32 + g * 8 + i;
            wf1pk[e] = bf16_rn(wc1[(size_t)hid * 2048 + k]);
        } else {
            int e = (bid - 2920) * 256 + t;
            int i  = e & 7;
            int o  = (e >> 3) & 127;
            int g  = (e >> 10) & 3;
            int kc = e >> 12;
            int k = kc * 32 + g * 8 + i;
            wf2pk[e] = bf16_rn(wc2[(size_t)o * 256 + k]);
        }
        return;
    }

    __shared__ float img[34 * 66];
    __shared__ float ws[32 * 9];
    __shared__ float bs[32];
    const int cbid = blockIdx.x - np;
    const int bl = cbid >> 1;
    const int yb = cbid & 1;
    const int b = b0 + bl;

    for (int i = t; i < 34 * 66; i += 256) img[i] = 0.0f;
    for (int i = t; i < 288; i += 256) ws[i] = w1[i];
    if (t < 32) bs[t] = b1[t];
    __syncthreads();

    const float* xb = x + (size_t)b * 8192;
    const int rbase = yb * 32 - 1;
    for (int s = t; s < 4096; s += 256) {
        float xi = xb[s];
        float xq = xb[4096 + s];
        int ii = (int)(xi * 16.0f + 32.0f);
        int qi = (int)(xq * 16.0f + 32.0f);
        ii = min(max(ii, 0), 63);
        qi = min(max(qi, 0), 63);
        int r = qi - rbase;
        if (r >= 0 && r < 34) img[r * 66 + (ii + 1)] = 1.0f;
    }
    __syncthreads();

    const float alpha = a1[0];
    unsigned short* ob = out1 + (size_t)bl * 32768;
    for (int i = 0; i < 2; ++i) {
        int p = i * 256 + t;
        int pyl = p >> 5, px = p & 31;
        float v[4][4];
        #pragma unroll
        for (int r = 0; r < 4; ++r)
            #pragma unroll
            for (int c = 0; c < 4; ++c)
                v[r][c] = img[(2 * pyl + r) * 66 + (2 * px + c)];
        const int pg = (yb * 16 + pyl) * 32 + px;
        unsigned short* dst = ob + (size_t)pg * 32;
        #pragma unroll 2
        for (int c4 = 0; c4 < 8; ++c4) {
            float o4[4];
            #pragma unroll
            for (int h = 0; h < 4; ++h) {
                const int c = c4 * 4 + h;
                float w[9];
                #pragma unroll
                for (int k = 0; k < 9; ++k) w[k] = ws[c * 9 + k];
                float s00 = 0.f, s01 = 0.f, s10 = 0.f, s11 = 0.f;
                #pragma unroll
                for (int ky = 0; ky < 3; ++ky)
                    #pragma unroll
                    for (int kx = 0; kx < 3; ++kx) {
                        float wk = w[ky * 3 + kx];
                        s00 = fmaf(v[ky][kx],         wk, s00);
                        s01 = fmaf(v[ky][kx + 1],     wk, s01);
                        s10 = fmaf(v[ky + 1][kx],     wk, s10);
                        s11 = fmaf(v[ky + 1][kx + 1], wk, s11);
                    }
                float bb = bs[c];
                o4[h] = 0.25f * (prelu(s00 + bb, alpha) + prelu(s01 + bb, alpha) +
                                 prelu(s10 + bb, alpha) + prelu(s11 + bb, alpha));
            }
            u32x2 q = {pack2(o4[0], o4[1]), pack2(o4[2], o4[3])};
            *reinterpret_cast<u32x2*>(dst + c4 * 4) = q;
        }
    }
}

// ---------------- Kernel 2: conv2 via 32x32x16 MFMA, dy-hoisted rows ----------------
__global__ __launch_bounds__(512) void k_conv2_mfma(
    const unsigned short* __restrict__ in1, const unsigned short* __restrict__ wpk,
    const float* __restrict__ b2, const float* __restrict__ a2,
    unsigned short* __restrict__ out2)
{
    __shared__ __align__(16) unsigned short lb[4 * 18 * 36 * 8]; // 41.5 KB [cg][ly][sx][i8]
    __shared__ float bs[64];
    const int t = threadIdx.x;
    const int bl = blockIdx.x >> 1;
    const int yb = blockIdx.x & 1;
    const int lane = t & 63;
    const int q = t >> 6;
    const int hl = lane >> 5;
    const int c31 = lane & 31;

    if (t < 64) bs[t] = b2[t];

    const s16x8 zz = {0, 0, 0, 0, 0, 0, 0, 0};
    for (int idx = t; idx < 2592; idx += 512)
        reinterpret_cast<s16x8*>(lb)[idx] = zz;
    __syncthreads();

    for (int idx = t; idx < 576; idx += 512) {
        int ly = idx >> 5;
        int xx = idx & 31;
        int y = yb * 16 + ly - 1;
        if (y >= 0 && y < 32) {
            const s16x8* src = reinterpret_cast<const s16x8*>(
                in1 + ((size_t)bl * 1024 + y * 32 + xx) * 32);
            #pragma unroll
            for (int cg = 0; cg < 4; ++cg) {
                *reinterpret_cast<s16x8*>(&lb[((cg * 18 + ly) * 36 + (xx + 1)) * 8]) = src[cg];
            }
        }
    }
    __syncthreads();

    f32x16 acc[2][2];
    #pragma unroll
    for (int m = 0; m < 2; ++m)
        #pragma unroll
        for (int n = 0; n < 2; ++n)
            #pragma unroll
            for (int e = 0; e < 16; ++e) acc[m][n][e] = 0.0f;

    #pragma unroll
    for (int kkk = 0; kkk < 2; ++kkk) {
        const int g = kkk * 2 + hl;
        #pragma unroll
        for (int dx = 0; dx < 3; ++dx) {
            const int sx = c31 + dx;
            s16x8 breg[4];
            #pragma unroll
            for (int j = 0; j < 4; ++j)
                breg[j] = *reinterpret_cast<const s16x8*>(
                    &lb[((g * 18 + 2 * q + j) * 36 + sx) * 8]);
            #pragma unroll
            for (int dy = 0; dy < 3; ++dy) {
                const int tap = dy * 3 + dx;
                const unsigned short* wb =
                    wpk + ((size_t)(tap * 2 + kkk) * 2) * 512 + lane * 8;
                s16x8 a0 = *reinterpret_cast<const s16x8*>(wb);
                s16x8 a1 = *reinterpret_cast<const s16x8*>(wb + 512);
                acc[0][0] = __builtin_amdgcn_mfma_f32_32x32x16_bf16(a0, breg[dy],     acc[0][0], 0, 0, 0);
                acc[0][1] = __builtin_amdgcn_mfma_f32_32x32x16_bf16(a0, breg[dy + 1], acc[0][1], 0, 0, 0);
                acc[1][0] = __builtin_amdgcn_mfma_f32_32x32x16_bf16(a1, breg[dy],     acc[1][0], 0, 0, 0);
                acc[1][1] = __builtin_amdgcn_mfma_f32_32x32x16_bf16(a1, breg[dy + 1], acc[1][1], 0, 0, 0);
            }
        }
    }

    const float alpha = a2[0];
    const int gy = yb * 8 + q;
    const int gx = c31 >> 1;
    #pragma unroll
    for (int mt = 0; mt < 2; ++mt) {
        float sv[16];
        #pragma unroll
        for (int r = 0; r < 16; ++r) {
            const int co = mt * 32 + (r & 3) + 8 * (r >> 2) + 4 * hl;
            const float bb = bs[co];
            float s = prelu(acc[mt][0][r] + bb, alpha) + prelu(acc[mt][1][r] + bb, alpha);
            s += __shfl_xor(s, 1, 64);
            sv[r] = s * 0.25f;
        }
        if ((lane & 1) == 0) {
            unsigned short* dst = out2 + ((size_t)bl * 256 + gy * 16 + gx) * 64;
            #pragma unroll
            for (int rp = 0; rp < 8; ++rp) {
                const int r = rp * 2;
                const int co0 = mt * 32 + (r & 3) + 8 * (r >> 2) + 4 * hl;
                *reinterpret_cast<unsigned*>(dst + co0) = pack2(sv[r], sv[r + 1]);
            }
        }
    }
}

// ---------------- Kernel 3: conv3 via 16x16x32 MFMA, (mg,rq) wave split ----------------
// block = full image. LDS [g8][ly20][ax20][i8] = 51.2 KB. 8 waves = 2 co-halves x 4 row-quads.
// Per (kk,tap): 4 B-reads (deduped across co) + 4 A-reads (L1-deduped across rq), 16 MFMA.
__global__ __launch_bounds__(512) void k_conv3_mfma(
    const unsigned short* __restrict__ in2, const unsigned short* __restrict__ wpk,
    const float* __restrict__ b3, const float* __restrict__ a3,
    unsigned short* __restrict__ out3h, int b0)
{
    __shared__ __align__(16) unsigned short lb[8 * 20 * 20 * 8]; // 51.2 KB
    __shared__ float bs[128];

    const int t = threadIdx.x;
    const int bl = blockIdx.x;
    const int lane = t & 63;
    const int w = t >> 6;
    const int mg = w >> 2;        // 0..1 -> co 64-half (m-tiles mg*4 .. mg*4+3)
    const int rq = w & 3;         // 0..3 -> pre-pool rows 4rq..4rq+3, fy = rq
    const int lg = lane >> 4;
    const int lo16 = lane & 15;

    if (t < 128) bs[t] = b3[t];

    const s16x8 zz = {0, 0, 0, 0, 0, 0, 0, 0};
    for (int idx = t; idx < 3200; idx += 512)
        reinterpret_cast<s16x8*>(lb)[idx] = zz;
    __syncthreads();

    for (int idx = t; idx < 2048; idx += 512) {
        int g = idx >> 8;
        int pix = idx & 255;
        int row = pix >> 4;
        int xx = pix & 15;
        s16x8 v = *reinterpret_cast<const s16x8*>(
            in2 + ((size_t)bl * 256 + row * 16 + xx) * 64 + g * 8);
        *reinterpret_cast<s16x8*>(&lb[((g * 20 + (row + 2)) * 20 + (xx + 2)) * 8]) = v;
    }
    __syncthreads();

    const f32x4 zf = {0.f, 0.f, 0.f, 0.f};
    f32x4 acc[4][4];   // [mt][n]
    #pragma unroll
    for (int mt = 0; mt < 4; ++mt)
        #pragma unroll
        for (int n = 0; n < 4; ++n) acc[mt][n] = zf;

    for (int kk = 0; kk < 2; ++kk) {
        for (int tap = 0; tap < 25; ++tap) {
            const int dy = tap / 5, dx = tap - dy * 5;
            s16x8 bfr[4];
            #pragma unroll
            for (int n = 0; n < 4; ++n)
                bfr[n] = *reinterpret_cast<const s16x8*>(
                    &lb[(((kk * 4 + lg) * 20 + (4 * rq + n + dy)) * 20 + lo16 + dx) * 8]);
            #pragma unroll
            for (int mt = 0; mt < 4; ++mt) {
                const size_t wbase = ((size_t)(tap * 2 + kk) * 4 + lg) * 1024
                                   + (size_t)((mg * 4 + mt) * 16 + lo16) * 8;
                s16x8 a = *reinterpret_cast<const s16x8*>(wpk + wbase);
                #pragma unroll
                for (int n = 0; n < 4; ++n)
                    acc[mt][n] = __builtin_amdgcn_mfma_f32_16x16x32_bf16(a, bfr[n], acc[mt][n], 0, 0, 0);
            }
        }
    }

    const float alpha = a3[0];
    const int b = b0 + bl;
    const int fx = lo16 >> 2;
    #pragma unroll
    for (int mt = 0; mt < 4; ++mt) {
        const int cobase = mg * 64 + mt * 16 + lg * 4;
        #pragma unroll
        for (int r = 0; r < 4; ++r) {
            const float bb = bs[cobase + r];
            float s = 0.f;
            #pragma unroll
            for (int n = 0; n < 4; ++n) {
                float v = acc[mt][n][r] + bb;
                s += v > 0.f ? v : alpha * v;
            }
            s += __shfl_xor(s, 1, 64);
            s += __shfl_xor(s, 2, 64);
            if ((lane & 3) == 0)
                out3h[(size_t)b * 2048 + (cobase + r) * 16 + rq * 4 + fx] =
                    bf16_rn(s * 0.0625f);
        }
    }
}

// ---------------- Kernel 4: fused fc1 (K=2048) + prelu + fc2 (K=256) via MFMA ----------------
__global__ __launch_bounds__(512) void k_fc_mfma(
    const unsigned short* __restrict__ h, const unsigned short* __restrict__ w1pk,
    const float* __restrict__ bc1, const float* __restrict__ ac,
    const unsigned short* __restrict__ w2pk, const float* __restrict__ bc2,
    float* __restrict__ out)
{
    __shared__ __align__(16) unsigned short hid_lds[16][264];
    __shared__ float bs1[256];
    __shared__ float bs2[128];
    const int t = threadIdx.x;
    const int lane = t & 63;
    const int w = t >> 6;
    const int lg = lane >> 4;
    const int lo16 = lane & 15;

    if (t < 256) bs1[t] = bc1[t];
    if (t < 128) bs2[t] = bc2[t];

    const size_t rb = (size_t)blockIdx.x * 16 + lo16;

    const f32x4 zf = {0.f, 0.f, 0.f, 0.f};
    f32x4 acc1[2];
    acc1[0] = zf; acc1[1] = zf;

    const unsigned short* hrow = h + rb * 2048;
    #pragma unroll 2
    for (int kc = 0; kc < 64; ++kc) {
        s16x8 bfrag = *reinterpret_cast<const s16x8*>(hrow + kc * 32 + lg * 8);
        #pragma unroll
        for (int mt = 0; mt < 2; ++mt) {
            s16x8 afr = *reinterpret_cast<const s16x8*>(
                w1pk + ((size_t)(kc * 4 + lg) * 256 + (w * 2 + mt) * 16 + lo16) * 8);
            acc1[mt] = __builtin_amdgcn_mfma_f32_16x16x32_bf16(afr, bfrag, acc1[mt], 0, 0, 0);
        }
    }

    __syncthreads();
    const float alpha = ac[0];
    #pragma unroll
    for (int mt = 0; mt < 2; ++mt) {
        const int hid0 = (w * 2 + mt) * 16 + lg * 4;
        float v0 = prelu(acc1[mt][0] + bs1[hid0 + 0], alpha);
        float v1 = prelu(acc1[mt][1] + bs1[hid0 + 1], alpha);
        float v2 = prelu(acc1[mt][2] + bs1[hid0 + 2], alpha);
        float v3 = prelu(acc1[mt][3] + bs1[hid0 + 3], alpha);
        u32x2 q = {pack2(v0, v1), pack2(v2, v3)};
        *reinterpret_cast<u32x2*>(&hid_lds[lo16][hid0]) = q;
    }
    __syncthreads();

    f32x4 acc2 = zf;
    #pragma unroll
    for (int kc = 0; kc < 8; ++kc) {
        s16x8 bfrag = *reinterpret_cast<const s16x8*>(&hid_lds[lo16][kc * 32 + lg * 8]);
        s16x8 afr = *reinterpret_cast<const s16x8*>(
            w2pk + ((size_t)(kc * 4 + lg) * 128 + w * 16 + lo16) * 8);
        acc2 = __builtin_amdgcn_mfma_f32_16x16x32_bf16(afr, bfrag, acc2, 0, 0, 0);
    }

    const int o0 = w * 16 + lg * 4;
    #pragma unroll
    for (int r = 0; r < 4; ++r)
        out[rb * 128 + o0 + r] = acc2[r] + bs2[o0 + r];
}

extern "C" void kernel_launch(void* const* d_in, const int* in_sizes, int n_in,
                              void* d_out, int out_size, void* d_ws, size_t ws_size,
                              hipStream_t stream) {
    const float* x   = (const float*)d_in[0];
    const float* w1  = (const float*)d_in[1];
    const float* b1  = (const float*)d_in[2];
    const float* a1  = (const float*)d_in[3];
    const float* w2  = (const float*)d_in[4];
    const float* b2  = (const float*)d_in[5];
    const float* a2  = (const float*)d_in[6];
    const float* w3  = (const float*)d_in[7];
    const float* b3  = (const float*)d_in[8];
    const float* a3  = (const float*)d_in[9];
    const float* wc1 = (const float*)d_in[10];
    const float* bc1 = (const float*)d_in[11];
    const float* ac  = (const float*)d_in[12];
    const float* wc2 = (const float*)d_in[13];
    const float* bc2 = (const float*)d_in[14];
    float* out = (float*)d_out;

    const size_t OUT3_BYTES = (size_t)1024 * 2048 * 2;      // 4 MB (bf16)
    const size_t W3PK = (size_t)204800 * 2;                 // 400 KB
    const size_t W2PK = (size_t)18432 * 2;                  // 36 KB
    const size_t WFC1 = (size_t)524288 * 2;                 // 1 MB
    const size_t WFC2 = (size_t)32768 * 2;                  // 64 KB
    const size_t FIXED = OUT3_BYTES + W3PK + W2PK + WFC1 + WFC2;
    int C = 1024;
    while (C > 1 && FIXED + (size_t)C * (65536 + 32768) > ws_size) C >>= 1;

    char* p = (char*)d_ws;
    unsigned short* out3h = (unsigned short*)p;  p += OUT3_BYTES;
    unsigned short* w3pk  = (unsigned short*)p;  p += W3PK;
    unsigned short* w2pk  = (unsigned short*)p;  p += W2PK;
    unsigned short* wf1pk = (unsigned short*)p;  p += WFC1;
    unsigned short* wf2pk = (unsigned short*)p;  p += WFC2;
    unsigned short* out1  = (unsigned short*)p;  p += (size_t)C * 65536;
    unsigned short* out2  = (unsigned short*)p;

    const int nchunk = 1024 / C;
    for (int c = 0; c < nchunk; ++c) {
        int b0 = c * C;
        int np = (c == 0) ? 3048 : 0;
        k_front<<<np + 2 * C, 256, 0, stream>>>(
            x, w1, b1, a1, out1, b0, np,
            w3, w3pk, w2, w2pk, wc1, wf1pk, wc2, wf2pk);
        k_conv2_mfma<<<2 * C, 512, 0, stream>>>(out1, w2pk, b2, a2, out2);
        k_conv3_mfma<<<C, 512, 0, stream>>>(out2, w3pk, b3, a3, out3h, b0);
    }
    k_fc_mfma<<<64, 512, 0, stream>>>(out3h, wf1pk, bc1, ac, wf2pk, bc2, out);
}

// Round 14
// 230.989 us; speedup vs baseline: 1.0401x; 1.0401x over previous
//
#include <hip/hip_runtime.h>

// Constellation CNN. conv1 1-block/image 512t, conv2 32x32x16 (dy-hoisted),
// conv3 16x16x32 (R9 empirical-optimum form), fc fused MFMA. NHWC intermediates.

typedef short s16x8 __attribute__((ext_vector_type(8)));
typedef float f32x4 __attribute__((ext_vector_type(4)));
typedef float f32x16 __attribute__((ext_vector_type(16)));
typedef unsigned u32x4 __attribute__((ext_vector_type(4)));
typedef unsigned u32x2 __attribute__((ext_vector_type(2)));

__device__ __forceinline__ float prelu(float v, float a) {
    return v > 0.0f ? v : a * v;
}
__device__ __forceinline__ unsigned short bf16_rn(float x) {
    union { float f; unsigned u; } a; a.f = x;
    unsigned r = a.u + 0x7FFF + ((a.u >> 16) & 1);
    return (unsigned short)(r >> 16);
}
__device__ __forceinline__ unsigned pack2(float lo, float hi) {
    return (unsigned)bf16_rn(lo) | ((unsigned)bf16_rn(hi) << 16);
}

// ---------------- Kernel 1: [prepack blocks, 512t] + [scatter->conv1->pool, 1 blk/img] ----
// np = 1524 prepack blocks on first chunk: w3pk 400, w2pk 36, wf1pk 1024, wf2pk 64.
__global__ __launch_bounds__(512) void k_front(
    const float* __restrict__ x, const float* __restrict__ w1,
    const float* __restrict__ b1, const float* __restrict__ a1,
    unsigned short* __restrict__ out1, int b0, int np,
    const float* __restrict__ w3, unsigned short* __restrict__ w3pk,
    const float* __restrict__ w2, unsigned short* __restrict__ w2pk,
    const float* __restrict__ wc1, unsigned short* __restrict__ wf1pk,
    const float* __restrict__ wc2, unsigned short* __restrict__ wf2pk)
{
    const int t = threadIdx.x;
    if ((int)blockIdx.x < np) {
        const int bid = blockIdx.x;
        if (bid < 400) {                       // conv3: [tap25][kk2][g4][co128][i8]
            int e = bid * 512 + t;
            int i  = e & 7;
            int co = (e >> 3) & 127;
            int g  = (e >> 10) & 3;
            int kk = (e >> 12) & 1;
            int tp = e >> 13;
            int ci = kk * 32 + g * 8 + i;
            w3pk[e] = bf16_rn(w3[((size_t)co * 64 + ci) * 25 + tp]);
        } else if (bid < 436) {                // conv2: [tap9][kkk2][mt2][l64][i8]
            int e = (bid - 400) * 512 + t;
            int i   = e & 7;
            int l   = (e >> 3) & 63;
            int mt  = (e >> 9) & 1;
            int kkk = (e >> 10) & 1;
            int tap = e >> 11;
            int co = mt * 32 + (l & 31);
            int ci = kkk * 16 + (l >> 5) * 8 + i;
            w2pk[e] = bf16_rn(w2[((size_t)co * 32 + ci) * 9 + tap]);
        } else if (bid < 1460) {               // fc1: [kc64][g4][hid256][i8]
            int e = (bid - 436) * 512 + t;
            int i   = e & 7;
            int hid = (e >> 3) & 255;
            int g   = (e >> 11) & 3;
            int kc  = e >> 13;
            int k = kc * 32 + g * 8 + i;
            wf1pk[e] = bf16_rn(wc1[(size_t)hid * 2048 + k]);
        } else {                               // fc2: [kc8][g4][o128][i8]
            int e = (bid - 1460) * 512 + t;
            int i  = e & 7;
            int o  = (e >> 3) & 127;
            int g  = (e >> 10) & 3;
            int kc = e >> 12;
            int k = kc * 32 + g * 8 + i;
            wf2pk[e] = bf16_rn(wc2[(size_t)o * 256 + k]);
        }
        return;
    }

    __shared__ float img[66 * 66];   // full padded constellation, 17.4 KB
    __shared__ float ws[32 * 9];
    __shared__ float bs[32];
    const int bl = blockIdx.x - np;
    const int b = b0 + bl;

    for (int i = t; i < 66 * 66; i += 512) img[i] = 0.0f;
    if (t < 288) ws[t] = w1[t];
    if (t < 32) bs[t] = b1[t];
    __syncthreads();

    const float* xb = x + (size_t)b * 8192;
    for (int s = t; s < 4096; s += 512) {
        float xi = xb[s];
        float xq = xb[4096 + s];
        int ii = (int)(xi * 16.0f + 32.0f);   // trunc toward zero == astype(int32)
        int qi = (int)(xq * 16.0f + 32.0f);
        ii = min(max(ii, 0), 63);
        qi = min(max(qi, 0), 63);
        img[(qi + 1) * 66 + (ii + 1)] = 1.0f; // all writes 1.0 -> benign race
    }
    __syncthreads();

    const float alpha = a1[0];
    unsigned short* ob = out1 + (size_t)bl * 32768;
    #pragma unroll
    for (int i = 0; i < 2; ++i) {
        int p = i * 512 + t;                  // pooled px 0..1023
        int py = p >> 5, px = p & 31;
        float v[4][4];
        #pragma unroll
        for (int r = 0; r < 4; ++r)
            #pragma unroll
            for (int c = 0; c < 4; ++c)
                v[r][c] = img[(2 * py + r) * 66 + (2 * px + c)];
        unsigned short* dst = ob + (size_t)p * 32;
        #pragma unroll 2
        for (int c4 = 0; c4 < 8; ++c4) {
            float o4[4];
            #pragma unroll
            for (int h = 0; h < 4; ++h) {
                const int c = c4 * 4 + h;
                float w[9];
                #pragma unroll
                for (int k = 0; k < 9; ++k) w[k] = ws[c * 9 + k];
                float s00 = 0.f, s01 = 0.f, s10 = 0.f, s11 = 0.f;
                #pragma unroll
                for (int ky = 0; ky < 3; ++ky)
                    #pragma unroll
                    for (int kx = 0; kx < 3; ++kx) {
                        float wk = w[ky * 3 + kx];
                        s00 = fmaf(v[ky][kx],         wk, s00);
                        s01 = fmaf(v[ky][kx + 1],     wk, s01);
                        s10 = fmaf(v[ky + 1][kx],     wk, s10);
                        s11 = fmaf(v[ky + 1][kx + 1], wk, s11);
                    }
                float bb = bs[c];
                o4[h] = 0.25f * (prelu(s00 + bb, alpha) + prelu(s01 + bb, alpha) +
                                 prelu(s10 + bb, alpha) + prelu(s11 + bb, alpha));
            }
            u32x2 q = {pack2(o4[0], o4[1]), pack2(o4[2], o4[3])};
            *reinterpret_cast<u32x2*>(dst + c4 * 4) = q;
        }
    }
}

// ---------------- Kernel 2: conv2 via 32x32x16 MFMA, dy-hoisted rows ----------------
__global__ __launch_bounds__(512) void k_conv2_mfma(
    const unsigned short* __restrict__ in1, const unsigned short* __restrict__ wpk,
    const float* __restrict__ b2, const float* __restrict__ a2,
    unsigned short* __restrict__ out2)
{
    __shared__ __align__(16) unsigned short lb[4 * 18 * 36 * 8]; // 41.5 KB [cg][ly][sx][i8]
    __shared__ float bs[64];
    const int t = threadIdx.x;
    const int bl = blockIdx.x >> 1;
    const int yb = blockIdx.x & 1;
    const int lane = t & 63;
    const int q = t >> 6;
    const int hl = lane >> 5;
    const int c31 = lane & 31;

    if (t < 64) bs[t] = b2[t];

    const s16x8 zz = {0, 0, 0, 0, 0, 0, 0, 0};
    for (int idx = t; idx < 2592; idx += 512)
        reinterpret_cast<s16x8*>(lb)[idx] = zz;
    __syncthreads();

    for (int idx = t; idx < 576; idx += 512) {
        int ly = idx >> 5;
        int xx = idx & 31;
        int y = yb * 16 + ly - 1;
        if (y >= 0 && y < 32) {
            const s16x8* src = reinterpret_cast<const s16x8*>(
                in1 + ((size_t)bl * 1024 + y * 32 + xx) * 32);
            #pragma unroll
            for (int cg = 0; cg < 4; ++cg) {
                *reinterpret_cast<s16x8*>(&lb[((cg * 18 + ly) * 36 + (xx + 1)) * 8]) = src[cg];
            }
        }
    }
    __syncthreads();

    f32x16 acc[2][2];
    #pragma unroll
    for (int m = 0; m < 2; ++m)
        #pragma unroll
        for (int n = 0; n < 2; ++n)
            #pragma unroll
            for (int e = 0; e < 16; ++e) acc[m][n][e] = 0.0f;

    #pragma unroll
    for (int kkk = 0; kkk < 2; ++kkk) {
        const int g = kkk * 2 + hl;
        #pragma unroll
        for (int dx = 0; dx < 3; ++dx) {
            const int sx = c31 + dx;
            s16x8 breg[4];
            #pragma unroll
            for (int j = 0; j < 4; ++j)
                breg[j] = *reinterpret_cast<const s16x8*>(
                    &lb[((g * 18 + 2 * q + j) * 36 + sx) * 8]);
            #pragma unroll
            for (int dy = 0; dy < 3; ++dy) {
                const int tap = dy * 3 + dx;
                const unsigned short* wb =
                    wpk + ((size_t)(tap * 2 + kkk) * 2) * 512 + lane * 8;
                s16x8 a0 = *reinterpret_cast<const s16x8*>(wb);
                s16x8 a1 = *reinterpret_cast<const s16x8*>(wb + 512);
                acc[0][0] = __builtin_amdgcn_mfma_f32_32x32x16_bf16(a0, breg[dy],     acc[0][0], 0, 0, 0);
                acc[0][1] = __builtin_amdgcn_mfma_f32_32x32x16_bf16(a0, breg[dy + 1], acc[0][1], 0, 0, 0);
                acc[1][0] = __builtin_amdgcn_mfma_f32_32x32x16_bf16(a1, breg[dy],     acc[1][0], 0, 0, 0);
                acc[1][1] = __builtin_amdgcn_mfma_f32_32x32x16_bf16(a1, breg[dy + 1], acc[1][1], 0, 0, 0);
            }
        }
    }

    const float alpha = a2[0];
    const int gy = yb * 8 + q;
    const int gx = c31 >> 1;
    #pragma unroll
    for (int mt = 0; mt < 2; ++mt) {
        float sv[16];
        #pragma unroll
        for (int r = 0; r < 16; ++r) {
            const int co = mt * 32 + (r & 3) + 8 * (r >> 2) + 4 * hl;
            const float bb = bs[co];
            float s = prelu(acc[mt][0][r] + bb, alpha) + prelu(acc[mt][1][r] + bb, alpha);
            s += __shfl_xor(s, 1, 64);
            sv[r] = s * 0.25f;
        }
        if ((lane & 1) == 0) {
            unsigned short* dst = out2 + ((size_t)bl * 256 + gy * 16 + gx) * 64;
            #pragma unroll
            for (int rp = 0; rp < 8; ++rp) {
                const int r = rp * 2;
                const int co0 = mt * 32 + (r & 3) + 8 * (r >> 2) + 4 * hl;
                *reinterpret_cast<unsigned*>(dst + co0) = pack2(sv[r], sv[r + 1]);
            }
        }
    }
}

// ---------------- Kernel 3: conv3 via 16x16x32 MFMA (R9 empirical-optimum form) ----------
// block = full image. LDS [g8][ly20][ax20][i8] = 51.2 KB. 8 waves = 4 m-pairs x 2 row-halves.
__global__ __launch_bounds__(512) void k_conv3_mfma(
    const unsigned short* __restrict__ in2, const unsigned short* __restrict__ wpk,
    const float* __restrict__ b3, const float* __restrict__ a3,
    unsigned short* __restrict__ out3h, int b0)
{
    __shared__ __align__(16) unsigned short lb[8 * 20 * 20 * 8]; // 51.2 KB
    __shared__ float bs[128];

    const int t = threadIdx.x;
    const int bl = blockIdx.x;
    const int lane = t & 63;
    const int w = t >> 6;
    const int mp = w >> 1;        // 0..3 -> m-tiles {2mp, 2mp+1}
    const int nh = w & 1;         // 0..1 -> pre-pool rows nh*8 .. nh*8+7
    const int lg = lane >> 4;
    const int lo16 = lane & 15;

    if (t < 128) bs[t] = b3[t];

    const s16x8 zz = {0, 0, 0, 0, 0, 0, 0, 0};
    for (int idx = t; idx < 3200; idx += 512)
        reinterpret_cast<s16x8*>(lb)[idx] = zz;
    __syncthreads();

    for (int idx = t; idx < 2048; idx += 512) {
        int g = idx >> 8;
        int pix = idx & 255;
        int row = pix >> 4;
        int xx = pix & 15;
        s16x8 v = *reinterpret_cast<const s16x8*>(
            in2 + ((size_t)bl * 256 + row * 16 + xx) * 64 + g * 8);
        *reinterpret_cast<s16x8*>(&lb[((g * 20 + (row + 2)) * 20 + (xx + 2)) * 8]) = v;
    }
    __syncthreads();

    const f32x4 zf = {0.f, 0.f, 0.f, 0.f};
    f32x4 acc[2][8];
    #pragma unroll
    for (int m = 0; m < 2; ++m)
        #pragma unroll
        for (int n = 0; n < 8; ++n) acc[m][n] = zf;

    for (int kk = 0; kk < 2; ++kk) {
        for (int tap = 0; tap < 25; ++tap) {
            int dy = tap / 5, dx = tap - dy * 5;
            const size_t wbase = ((size_t)(tap * 2 + kk) * 4 + lg) * 1024
                               + (size_t)(mp * 32 + lo16) * 8;
            s16x8 a0 = *reinterpret_cast<const s16x8*>(wpk + wbase);
            s16x8 a1 = *reinterpret_cast<const s16x8*>(wpk + wbase + 128);
            #pragma unroll
            for (int n = 0; n < 8; ++n) {
                int ly = nh * 8 + n + dy;          // 0..19
                int ax = lo16 + dx;                // 0..19
                s16x8 bfrag = *reinterpret_cast<const s16x8*>(
                    &lb[(((kk * 4 + lg) * 20 + ly) * 20 + ax) * 8]);
                acc[0][n] = __builtin_amdgcn_mfma_f32_16x16x32_bf16(a0, bfrag, acc[0][n], 0, 0, 0);
                acc[1][n] = __builtin_amdgcn_mfma_f32_16x16x32_bf16(a1, bfrag, acc[1][n], 0, 0, 0);
            }
        }
    }

    const float alpha = a3[0];
    const int b = b0 + bl;
    const int fx = lo16 >> 2;
    #pragma unroll
    for (int m = 0; m < 2; ++m) {
        const int cobase = mp * 32 + m * 16 + lg * 4;
        #pragma unroll
        for (int r = 0; r < 4; ++r) {
            float bb = bs[cobase + r];
            #pragma unroll
            for (int half = 0; half < 2; ++half) {
                float s = 0.f;
                #pragma unroll
                for (int j = 0; j < 4; ++j) {
                    float v = acc[m][half * 4 + j][r] + bb;
                    s += v > 0.f ? v : alpha * v;
                }
                s += __shfl_xor(s, 1, 64);
                s += __shfl_xor(s, 2, 64);
                if ((lane & 3) == 0) {
                    int fy = nh * 2 + half;
                    out3h[(size_t)b * 2048 + (cobase + r) * 16 + fy * 4 + fx] =
                        bf16_rn(s * 0.0625f);
                }
            }
        }
    }
}

// ---------------- Kernel 4: fused fc1 (K=2048) + prelu + fc2 (K=256) via MFMA ----------------
__global__ __launch_bounds__(512) void k_fc_mfma(
    const unsigned short* __restrict__ h, const unsigned short* __restrict__ w1pk,
    const float* __restrict__ bc1, const float* __restrict__ ac,
    const unsigned short* __restrict__ w2pk, const float* __restrict__ bc2,
    float* __restrict__ out)
{
    __shared__ __align__(16) unsigned short hid_lds[16][264];
    __shared__ float bs1[256];
    __shared__ float bs2[128];
    const int t = threadIdx.x;
    const int lane = t & 63;
    const int w = t >> 6;
    const int lg = lane >> 4;
    const int lo16 = lane & 15;

    if (t < 256) bs1[t] = bc1[t];
    if (t < 128) bs2[t] = bc2[t];

    const size_t rb = (size_t)blockIdx.x * 16 + lo16;

    const f32x4 zf = {0.f, 0.f, 0.f, 0.f};
    f32x4 acc1[2];
    acc1[0] = zf; acc1[1] = zf;

    const unsigned short* hrow = h + rb * 2048;
    #pragma unroll 2
    for (int kc = 0; kc < 64; ++kc) {
        s16x8 bfrag = *reinterpret_cast<const s16x8*>(hrow + kc * 32 + lg * 8);
        #pragma unroll
        for (int mt = 0; mt < 2; ++mt) {
            s16x8 afr = *reinterpret_cast<const s16x8*>(
                w1pk + ((size_t)(kc * 4 + lg) * 256 + (w * 2 + mt) * 16 + lo16) * 8);
            acc1[mt] = __builtin_amdgcn_mfma_f32_16x16x32_bf16(afr, bfrag, acc1[mt], 0, 0, 0);
        }
    }

    __syncthreads();
    const float alpha = ac[0];
    #pragma unroll
    for (int mt = 0; mt < 2; ++mt) {
        const int hid0 = (w * 2 + mt) * 16 + lg * 4;
        float v0 = prelu(acc1[mt][0] + bs1[hid0 + 0], alpha);
        float v1 = prelu(acc1[mt][1] + bs1[hid0 + 1], alpha);
        float v2 = prelu(acc1[mt][2] + bs1[hid0 + 2], alpha);
        float v3 = prelu(acc1[mt][3] + bs1[hid0 + 3], alpha);
        u32x2 q = {pack2(v0, v1), pack2(v2, v3)};
        *reinterpret_cast<u32x2*>(&hid_lds[lo16][hid0]) = q;
    }
    __syncthreads();

    f32x4 acc2 = zf;
    #pragma unroll
    for (int kc = 0; kc < 8; ++kc) {
        s16x8 bfrag = *reinterpret_cast<const s16x8*>(&hid_lds[lo16][kc * 32 + lg * 8]);
        s16x8 afr = *reinterpret_cast<const s16x8*>(
            w2pk + ((size_t)(kc * 4 + lg) * 128 + w * 16 + lo16) * 8);
        acc2 = __builtin_amdgcn_mfma_f32_16x16x32_bf16(afr, bfrag, acc2, 0, 0, 0);
    }

    const int o0 = w * 16 + lg * 4;
    #pragma unroll
    for (int r = 0; r < 4; ++r)
        out[rb * 128 + o0 + r] = acc2[r] + bs2[o0 + r];
}

extern "C" void kernel_launch(void* const* d_in, const int* in_sizes, int n_in,
                              void* d_out, int out_size, void* d_ws, size_t ws_size,
                              hipStream_t stream) {
    const float* x   = (const float*)d_in[0];
    const float* w1  = (const float*)d_in[1];
    const float* b1  = (const float*)d_in[2];
    const float* a1  = (const float*)d_in[3];
    const float* w2  = (const float*)d_in[4];
    const float* b2  = (const float*)d_in[5];
    const float* a2  = (const float*)d_in[6];
    const float* w3  = (const float*)d_in[7];
    const float* b3  = (const float*)d_in[8];
    const float* a3  = (const float*)d_in[9];
    const float* wc1 = (const float*)d_in[10];
    const float* bc1 = (const float*)d_in[11];
    const float* ac  = (const float*)d_in[12];
    const float* wc2 = (const float*)d_in[13];
    const float* bc2 = (const float*)d_in[14];
    float* out = (float*)d_out;

    const size_t OUT3_BYTES = (size_t)1024 * 2048 * 2;      // 4 MB (bf16)
    const size_t W3PK = (size_t)204800 * 2;                 // 400 KB
    const size_t W2PK = (size_t)18432 * 2;                  // 36 KB
    const size_t WFC1 = (size_t)524288 * 2;                 // 1 MB
    const size_t WFC2 = (size_t)32768 * 2;                  // 64 KB
    const size_t FIXED = OUT3_BYTES + W3PK + W2PK + WFC1 + WFC2;
    int C = 1024;
    while (C > 1 && FIXED + (size_t)C * (65536 + 32768) > ws_size) C >>= 1;

    char* p = (char*)d_ws;
    unsigned short* out3h = (unsigned short*)p;  p += OUT3_BYTES;
    unsigned short* w3pk  = (unsigned short*)p;  p += W3PK;
    unsigned short* w2pk  = (unsigned short*)p;  p += W2PK;
    unsigned short* wf1pk = (unsigned short*)p;  p += WFC1;
    unsigned short* wf2pk = (unsigned short*)p;  p += WFC2;
    unsigned short* out1  = (unsigned short*)p;  p += (size_t)C * 65536;
    unsigned short* out2  = (unsigned short*)p;

    const int nchunk = 1024 / C;
    for (int c = 0; c < nchunk; ++c) {
        int b0 = c * C;
        int np = (c == 0) ? 1524 : 0;
        k_front<<<np + C, 512, 0, stream>>>(
            x, w1, b1, a1, out1, b0, np,
            w3, w3pk, w2, w2pk, wc1, wf1pk, wc2, wf2pk);
        k_conv2_mfma<<<2 * C, 512, 0, stream>>>(out1, w2pk, b2, a2, out2);
        k_conv3_mfma<<<C, 512, 0, stream>>>(out2, w3pk, b3, a3, out3h, b0);
    }
    k_fc_mfma<<<64, 512, 0, stream>>>(out3h, wf1pk, bc1, ac, wf2pk, bc2, out);
}